// Round 14
// baseline (153.403 us; speedup 1.0000x reference)
//
#include <hip/hip_runtime.h>
#include <hip/hip_bf16.h>

// Per (b,c) slice: S = (Q K^T)*di ; A = softmax_rows(S) ; out[i,j] = sum_k A[j,k] V[i,k]
// FLASH, wave-level j-split (NO mm1 duplication):
//  block = slice x 128 j (2 blocks/slice, XCD-paired), 512 thr / 8 waves.
//  wave owns 16 j (j = j0 + 16wv + l15). Per 64-k chunk:
//   stage K[64x256]+V[256x64] fp16 (BOTH double-buffered, 1 barrier/chunk) ->
//   S^T frags = mfma16(K, Q): D col = j = l15 -> lane owns full j-column ->
//   online softmax: 16 in-lane + shfl_xor(16,32) over the 4 l4-lanes ->
//   P packed to a 2KB WAVE-PRIVATE LDS tile (no barrier, lgkmcnt only) ->
//   mm2 partial: out[ib] += mfma16(V[ib], Pfrag). 4 barriers total.
//  epilogue: out/l. LDS 144KB; regs ~200 (out[16] in AGPR); 1 block/CU.

typedef __attribute__((ext_vector_type(8))) _Float16 f16x8;
typedef __attribute__((ext_vector_type(2))) __fp16 fp16v2;
typedef __attribute__((ext_vector_type(4))) float f32x4;
typedef __attribute__((ext_vector_type(2))) unsigned u32x2;

#define BARRIER() asm volatile("s_waitcnt lgkmcnt(0)\n\ts_barrier" ::: "memory")

__device__ __forceinline__ f32x4 mfma16h(f16x8 a, f16x8 b, f32x4 c) {
  return __builtin_amdgcn_mfma_f32_16x16x32_f16(a, b, c, 0, 0, 0);
}
__device__ __forceinline__ f16x8 cvt8(f32x4 a, f32x4 b) {
  f16x8 r;
  r[0] = (_Float16)a[0]; r[1] = (_Float16)a[1];
  r[2] = (_Float16)a[2]; r[3] = (_Float16)a[3];
  r[4] = (_Float16)b[0]; r[5] = (_Float16)b[1];
  r[6] = (_Float16)b[2]; r[7] = (_Float16)b[3];
  return r;
}
__device__ __forceinline__ f16x8 cvt8s(f32x4 a, f32x4 b, float s) {
  f16x8 r;
  r[0] = (_Float16)(a[0] * s); r[1] = (_Float16)(a[1] * s);
  r[2] = (_Float16)(a[2] * s); r[3] = (_Float16)(a[3] * s);
  r[4] = (_Float16)(b[0] * s); r[5] = (_Float16)(b[1] * s);
  r[6] = (_Float16)(b[2] * s); r[7] = (_Float16)(b[3] * s);
  return r;
}
__device__ __forceinline__ unsigned pk2(float a, float b) {
  fp16v2 h = __builtin_amdgcn_cvt_pkrtz(a, b);
  return __builtin_bit_cast(unsigned, h);
}
// K tile [64 k][256 w] fp16, 512B rows, 32 slots: XOR 4 row bits -> 2 lanes/slot
__device__ __forceinline__ int swzK(int row, int byteCol) {
  return row * 512 + (byteCol ^ ((row & 15) << 4));
}
// V tile [256 i][64 k] fp16, 128B rows, 8 slots: XOR 3 row bits (bank-floor)
__device__ __forceinline__ int swzV(int row, int byteCol) {
  return row * 128 + (byteCol ^ ((row & 7) << 4));
}

__global__ __launch_bounds__(512, 2) void attn_flash2(
    const float* __restrict__ Q, const float* __restrict__ K,
    const float* __restrict__ V, const float* __restrict__ di,
    float* __restrict__ out) {
  __shared__ short Kl[2][64 * 256];   // 2 x 32KB fp16
  __shared__ short Vl[2][256 * 64];   // 2 x 32KB fp16
  __shared__ short Pl[8][16 * 64];    // 8 waves x 2KB, wave-private

  const int t = threadIdx.x;
  const int lane = t & 63;
  const int wv = t >> 6;          // 0..7 = j-group
  const int l15 = lane & 15;
  const int l4 = lane >> 4;       // 0..3 (full 2 bits)

  // 2 sibling blocks of one slice share bid%8 -> same XCD L2
  const int bid = blockIdx.x;
  const int bc = (bid >> 4) * 8 + (bid & 7);  // slice 0..511
  const int j0 = ((bid >> 3) & 1) << 7;       // 0 or 128

  const float dival = di[0];
  const size_t base = (size_t)bc << 16;
  const float* Qs = Q + base;
  const float* Ks = K + base;
  const float* Vs = V + base;
  float* Os = out + base;

  // staging maps
  const int kr = t >> 3, kc = (t & 7) * 32;  // K: row 0..63, 32 floats
  const int vr = t >> 1, vc = (t & 1) * 32;  // V: i-row 0..255, 32 floats

  // ---- prologue: issue chunk-0 loads; build Q fragments (pre-scaled) ----
  f32x4 kst[8], vst[8];
  {
    const float* p = Ks + kr * 256 + kc;
#pragma unroll
    for (int e = 0; e < 8; ++e) kst[e] = *(const f32x4*)(p + 4 * e);
    const float* v = Vs + (size_t)vr * 256 + vc;
#pragma unroll
    for (int e = 0; e < 8; ++e) vst[e] = *(const f32x4*)(v + 4 * e);
  }
  f16x8 qb[8];  // B-op: col j = l15, w = 32s + 8*l4 + e
  {
    const float* qrow = Qs + (size_t)(j0 + 16 * wv + l15) * 256 + 8 * l4;
#pragma unroll
    for (int s = 0; s < 8; ++s)
      qb[s] = cvt8s(*(const f32x4*)(qrow + 32 * s),
                    *(const f32x4*)(qrow + 32 * s + 4), dival);
  }

  f32x4 oacc[16];  // out[i = 16ib + 4*l4 + r][j = j0 + 16wv + l15]
#pragma unroll
  for (int i = 0; i < 16; ++i) oacc[i] = (f32x4){0.f, 0.f, 0.f, 0.f};
  float m = -1e30f, l = 0.f;

  char* pw = (char*)Pl[wv] + l15 * 128;  // wave-private P row (j = l15)

#pragma unroll
  for (int ch = 0; ch < 4; ++ch) {
    char* kb = (char*)Kl[ch & 1];
    char* vb = (char*)Vl[ch & 1];
    // ---- stage (compiler inserts vmcnt waits on kst/vst) ----
#pragma unroll
    for (int e = 0; e < 4; ++e)
      *(f16x8*)(kb + swzK(kr, 64 * (t & 7) + 16 * e)) =
          cvt8(kst[2 * e], kst[2 * e + 1]);
#pragma unroll
    for (int e = 0; e < 4; ++e)
      *(f16x8*)(vb + swzV(vr, 64 * (t & 1) + 16 * e)) =
          cvt8(vst[2 * e], vst[2 * e + 1]);
    BARRIER();  // the only barrier per chunk (dbuf both operands)
    if (ch < 3) {  // issue next chunk; in flight across this whole phase
      const float* p = Ks + (ch + 1) * 16384 + kr * 256 + kc;
#pragma unroll
      for (int e = 0; e < 8; ++e) kst[e] = *(const f32x4*)(p + 4 * e);
      const float* v = Vs + (size_t)vr * 256 + 64 * (ch + 1) + vc;
#pragma unroll
      for (int e = 0; e < 8; ++e) vst[e] = *(const f32x4*)(v + 4 * e);
    }
    // ---- mm1: S^T frags; s_[idx][r] = S[k = 64ch+16idx+4*l4+r][j] ----
    f32x4 s_[4];
#pragma unroll
    for (int i = 0; i < 4; ++i) s_[i] = (f32x4){0.f, 0.f, 0.f, 0.f};
    __builtin_amdgcn_s_setprio(1);
#pragma unroll
    for (int idx = 0; idx < 4; ++idx)
#pragma unroll
      for (int s = 0; s < 8; ++s) {
        f16x8 ka = *(const f16x8*)(kb + swzK(16 * idx + l15, 64 * s + 16 * l4));
        s_[idx] = mfma16h(ka, qb[s], s_[idx]);
      }
    __builtin_amdgcn_s_setprio(0);
    // ---- online softmax (j per lane; 4 l4-lanes share j via shfl) ----
    float cm = -1e30f;
#pragma unroll
    for (int idx = 0; idx < 4; ++idx)
#pragma unroll
      for (int r = 0; r < 4; ++r) cm = fmaxf(cm, s_[idx][r]);
    cm = fmaxf(cm, __shfl_xor(cm, 16));
    cm = fmaxf(cm, __shfl_xor(cm, 32));
    const float mn = fmaxf(m, cm);
    const float fac = __expf(m - mn);
    float ps = 0.f;
#pragma unroll
    for (int idx = 0; idx < 4; ++idx)
#pragma unroll
      for (int r = 0; r < 4; ++r) {
        s_[idx][r] = __expf(s_[idx][r] - mn);
        ps += s_[idx][r];
      }
    ps += __shfl_xor(ps, 16);
    ps += __shfl_xor(ps, 32);
    l = l * fac + ps;
    m = mn;
#pragma unroll
    for (int ib = 0; ib < 16; ++ib) oacc[ib] *= fac;
    // ---- pack P -> wave-private LDS tile [16 j][64 k] ----
#pragma unroll
    for (int idx = 0; idx < 4; ++idx) {
      u32x2 ww;
      ww[0] = pk2(s_[idx][0], s_[idx][1]);
      ww[1] = pk2(s_[idx][2], s_[idx][3]);
      *(u32x2*)(pw + ((32 * idx + 8 * l4) ^ ((l15 & 7) << 4))) = ww;
    }
    // ---- mm2: out[ib] += V[ib,kb] x P[kb] ----
    __builtin_amdgcn_s_setprio(1);
#pragma unroll
    for (int kb2 = 0; kb2 < 2; ++kb2) {
      f16x8 pf = *(const f16x8*)(pw + ((64 * kb2 + 16 * l4) ^ ((l15 & 7) << 4)));
#pragma unroll
      for (int ib = 0; ib < 16; ++ib) {
        f16x8 va =
            *(const f16x8*)(vb + swzV(16 * ib + l15, 64 * kb2 + 16 * l4));
        oacc[ib] = mfma16h(va, pf, oacc[ib]);
      }
    }
    __builtin_amdgcn_s_setprio(0);
  }

  // ---- epilogue: normalize by l, store ----
  const float inv = 1.0f / l;
  const int jcol = j0 + 16 * wv + l15;
#pragma unroll
  for (int ib = 0; ib < 16; ++ib)
#pragma unroll
    for (int r = 0; r < 4; ++r)
      Os[(size_t)(16 * ib + 4 * l4 + r) * 256 + jcol] = oacc[ib][r] * inv;
}

extern "C" void kernel_launch(void* const* d_in, const int* in_sizes, int n_in,
                              void* d_out, int out_size, void* d_ws,
                              size_t ws_size, hipStream_t stream) {
  const float* Q = (const float*)d_in[0];
  const float* K = (const float*)d_in[1];
  const float* V = (const float*)d_in[2];
  const float* di = (const float*)d_in[3];
  float* out = (float*)d_out;
  const int BC = in_sizes[0] / (256 * 256);  // 512 slices
  hipLaunchKernelGGL(attn_flash2, dim3(BC * 2), dim3(512), 0, stream, Q, K, V,
                     di, out);
}

// Round 15
// 105.286 us; speedup vs baseline: 1.4570x; 1.4570x over previous
//
#include <hip/hip_runtime.h>
#include <hip/hip_bf16.h>

// Per (b,c) slice: S = (Q K^T)*di ; A = softmax_rows(S) ; out[i,j] = sum_k A[j,k] V[i,k]
// ONE BLOCK PER SLICE: 1024 threads (16 waves), j-tile 256 -> K/V issued once.
// mm1: 8 chunks of 32 K-rows (Kbuf 2x16KB fp16 dbuf), 16x16x32 f16;
//      wave owns 16 j-rows; full-row softmax in registers (r13-verified).
// mm2: A-fragments PRELOADED TO REGISTERS (pb[16] = wave's 32j x 256k panel,
//      64 VGPR, one-time 16KB read) -> phases read only V from LDS.
//      8 phases = 4 i-chunks x 2 k-halves, V [64i][128k] fp16 double-buffered.
// Raw s_barrier + lgkmcnt(0); 2-deep register prefetch for K and V.
// LDS 160KB -> 1 block/CU (16 waves = 4/SIMD); VGPR target ~128.

typedef __attribute__((ext_vector_type(8))) _Float16 f16x8;
typedef __attribute__((ext_vector_type(4))) float f32x4;
typedef __attribute__((ext_vector_type(16))) float f32x16;

#define BARRIER() asm volatile("s_waitcnt lgkmcnt(0)\n\ts_barrier" ::: "memory")

__device__ __forceinline__ f32x4 mfma16h(f16x8 a, f16x8 b, f32x4 c) {
  return __builtin_amdgcn_mfma_f32_16x16x32_f16(a, b, c, 0, 0, 0);
}
__device__ __forceinline__ f32x16 mfma32h(f16x8 a, f16x8 b, f32x16 c) {
  return __builtin_amdgcn_mfma_f32_32x32x16_f16(a, b, c, 0, 0, 0);
}
__device__ __forceinline__ f16x8 cvt8(f32x4 a, f32x4 b) {
  f16x8 r;
  r[0] = (_Float16)a[0]; r[1] = (_Float16)a[1];
  r[2] = (_Float16)a[2]; r[3] = (_Float16)a[3];
  r[4] = (_Float16)b[0]; r[5] = (_Float16)b[1];
  r[6] = (_Float16)b[2]; r[7] = (_Float16)b[3];
  return r;
}
// 512B-row-stride fp16 tiles ([*][256]): XOR 4 row bits into the 16B-slot idx
__device__ __forceinline__ int swzA(int row, int byteCol) {
  return row * 512 + (byteCol ^ ((row & 15) << 4));
}
// 256B-row-stride fp16 tile ([64][128]): 4-bit XOR over 16 slots
__device__ __forceinline__ int swzV(int row, int byteCol) {
  return row * 256 + (byteCol ^ ((row & 15) << 4));
}

__global__ __launch_bounds__(1024, 4) void attn_fused15(
    const float* __restrict__ Q, const float* __restrict__ K,
    const float* __restrict__ V, const float* __restrict__ di,
    float* __restrict__ out) {
  __shared__ short Kbuf[2][32 * 256];  // 2 x 16KB fp16 K chunks; alias: Vlds
  __shared__ short Abuf[256 * 256];    // 128KB fp16 attn weights, swizzled
  short* Vlds0 = &Kbuf[0][0];          // mm2 V dbuf half 0 (16KB)
  short* Vlds1 = &Kbuf[1][0];          // mm2 V dbuf half 1 (16KB)

  const int t = threadIdx.x;
  const int lane = t & 63;
  const int wv = t >> 6;     // 0..15
  const int l15 = lane & 15;
  const int l4 = (lane >> 4) & 3;
  const int l31 = lane & 31;
  const int h5 = lane >> 5;

  const int bc = blockIdx.x;  // slice 0..511 (block owns whole slice)

  const float dival = di[0];
  const size_t base = (size_t)bc << 16;
  const float* Qs = Q + base;
  const float* Ks = K + base;
  const float* Vs = V + base;
  float* Os = out + base;

  // K staging: thread loads 8 consecutive floats of a 32x256 chunk,
  // writes one swizzled 16B fp16 slot.
  const int sr = t >> 5;          // row 0..31
  const int scf = (t & 31) << 3;  // float col (8 per thread)

  f32x4 kpA0, kpA1, kpB0, kpB1;  // 2-deep K prefetch (chunks ch, ch+1)
  {
    const float* p = Ks + sr * 256 + scf;
    kpA0 = *(const f32x4*)p;
    kpA1 = *(const f32x4*)(p + 4);
    kpB0 = *(const f32x4*)(p + 8192);
    kpB1 = *(const f32x4*)(p + 8192 + 4);
  }
  f16x8 qh[8];  // wave's 16 Q rows (A-op layout)
  {
    const float* qrow = Qs + (size_t)(16 * wv + l15) * 256 + 8 * l4;
#pragma unroll
    for (int s = 0; s < 8; ++s)
      qh[s] = cvt8(*(const f32x4*)(qrow + 32 * s),
                   *(const f32x4*)(qrow + 32 * s + 4));
  }

  f32x4 acc[16];  // S rows j=16wv+4l4+r ; cols k = 16*idx + l15
#pragma unroll
  for (int i = 0; i < 16; ++i) acc[i] = (f32x4){0.f, 0.f, 0.f, 0.f};

  // ---- matmul 1: 8 chunks of 32 k-rows, single barrier per chunk ----
#pragma unroll
  for (int ch = 0; ch < 8; ++ch) {
    short* kb = Kbuf[ch & 1];
    if ((ch & 1) == 0) {
      *(f16x8*)((char*)kb + swzA(sr, scf * 2)) = cvt8(kpA0, kpA1);
    } else {
      *(f16x8*)((char*)kb + swzA(sr, scf * 2)) = cvt8(kpB0, kpB1);
    }
    BARRIER();
    if (ch < 6) {  // prefetch chunk ch+2 into the freed parity regs
      const float* p = Ks + (ch + 2) * 8192 + sr * 256 + scf;
      if ((ch & 1) == 0) {
        kpA0 = *(const f32x4*)p;
        kpA1 = *(const f32x4*)(p + 4);
      } else {
        kpB0 = *(const f32x4*)p;
        kpB1 = *(const f32x4*)(p + 4);
      }
    }
    __builtin_amdgcn_s_setprio(1);
#pragma unroll
    for (int kf = 0; kf < 2; ++kf) {
      const int kr = 16 * kf + l15;
      f32x4 a = acc[2 * ch + kf];
#pragma unroll
      for (int s = 0; s < 8; ++s) {
        f16x8 bh =
            *(const f16x8*)((const char*)kb + swzA(kr, 64 * s + 16 * l4));
        a = mfma16h(qh[s], bh, a);
      }
      acc[2 * ch + kf] = a;
    }
    __builtin_amdgcn_s_setprio(0);
  }

  // ---- V prefetch for mm2 phases 0,1 (fly under softmax) ----
  const int vr = t >> 4;         // V-tile row 0..63
  const int vcf = (t & 15) * 8;  // float col within 128-col half
  f32x4 vpA[2], vpB[2];
  {
    const float* p = Vs + (size_t)vr * 256 + vcf;  // ic=0, kh=0
    vpA[0] = *(const f32x4*)p;
    vpA[1] = *(const f32x4*)(p + 4);
    const float* q = p + 128;  // ic=0, kh=1
    vpB[0] = *(const f32x4*)q;
    vpB[1] = *(const f32x4*)(q + 4);
  }

  // ---- softmax: full k per wave, in-register (r13-verified) ----
  float mx[4] = {-1e30f, -1e30f, -1e30f, -1e30f};
#pragma unroll
  for (int idx = 0; idx < 16; ++idx)
#pragma unroll
    for (int r = 0; r < 4; ++r) {
      acc[idx][r] *= dival;
      mx[r] = fmaxf(mx[r], acc[idx][r]);
    }
#pragma unroll
  for (int o = 1; o <= 8; o <<= 1)
#pragma unroll
    for (int r = 0; r < 4; ++r) mx[r] = fmaxf(mx[r], __shfl_xor(mx[r], o));
  float sm[4] = {0.f, 0.f, 0.f, 0.f};
#pragma unroll
  for (int idx = 0; idx < 16; ++idx)
#pragma unroll
    for (int r = 0; r < 4; ++r) {
      acc[idx][r] = __expf(acc[idx][r] - mx[r]);
      sm[r] += acc[idx][r];
    }
#pragma unroll
  for (int o = 1; o <= 8; o <<= 1)
#pragma unroll
    for (int r = 0; r < 4; ++r) sm[r] += __shfl_xor(sm[r], o);
#pragma unroll
  for (int r = 0; r < 4; ++r) sm[r] = 1.0f / sm[r];
#pragma unroll
  for (int idx = 0; idx < 16; ++idx)
#pragma unroll
    for (int r = 0; r < 4; ++r) {
      const int row = 16 * wv + 4 * l4 + r;
      *(_Float16*)((char*)Abuf + swzA(row, 2 * (16 * idx + l15))) =
          (_Float16)(acc[idx][r] * sm[r]);
    }
  BARRIER();  // A visible; all mm1 Kbuf reads done (Vlds alias safe)

  // ---- preload A-fragments to registers: wave's 32j x 256k panel ----
  const int ig = wv & 1;   // i 32-group within 64-row chunk
  const int jg = wv >> 1;  // j 32-group (0..7)
  f16x8 pb[16];            // pb[8*kh + kk] = A[32jg+l31][32(8kh+kk) + 16h5 ..]
#pragma unroll
  for (int kx = 0; kx < 16; ++kx)
    pb[kx] =
        *(const f16x8*)((const char*)Abuf + swzA(32 * jg + l31, 32 * kx + 16 * h5));

  // ---- matmul 2: 8 phases = 4 i-chunks(64) x 2 k-halves(128), V dbuf ----
  f32x16 o = {};
#pragma unroll
  for (int cc = 0; cc < 8; ++cc) {
    const int kh = cc & 1;
    short* vb = (cc & 1) ? Vlds1 : Vlds0;  // dbuf by parity
    if ((cc & 1) == 0) {
      *(f16x8*)((char*)vb + swzV(vr, 2 * vcf)) = cvt8(vpA[0], vpA[1]);
    } else {
      *(f16x8*)((char*)vb + swzV(vr, 2 * vcf)) = cvt8(vpB[0], vpB[1]);
    }
    BARRIER();  // single barrier per phase (dbuf)
    if (cc < 6) {  // prefetch phase cc+2 into freed parity regs
      const float* p = Vs + (size_t)(64 * ((cc + 2) >> 1) + vr) * 256 +
                       ((cc & 1) ? 128 : 0) + vcf;
      if ((cc & 1) == 0) {
        vpA[0] = *(const f32x4*)p;
        vpA[1] = *(const f32x4*)(p + 4);
      } else {
        vpB[0] = *(const f32x4*)p;
        vpB[1] = *(const f32x4*)(p + 4);
      }
    }
    __builtin_amdgcn_s_setprio(1);
#pragma unroll
    for (int kk = 0; kk < 8; ++kk) {
      f16x8 vfrag = *(const f16x8*)((const char*)vb +
                                    swzV(32 * ig + l31, 32 * kk + 16 * h5));
      o = mfma32h(vfrag, pb[8 * kh + kk], o);
    }
    __builtin_amdgcn_s_setprio(0);
    if (kh == 1) {  // both k-halves accumulated: store this i-chunk
      const int rbase = 64 * (cc >> 1) + 32 * ig + 4 * h5;
      const int col = 32 * jg + l31;
#pragma unroll
      for (int reg = 0; reg < 16; ++reg) {
        const int rw = (reg & 3) + 8 * (reg >> 2);
        Os[(size_t)(rbase + rw) * 256 + col] = o[reg];
      }
      o = (f32x16){};
    }
  }
}

extern "C" void kernel_launch(void* const* d_in, const int* in_sizes, int n_in,
                              void* d_out, int out_size, void* d_ws,
                              size_t ws_size, hipStream_t stream) {
  const float* Q = (const float*)d_in[0];
  const float* K = (const float*)d_in[1];
  const float* V = (const float*)d_in[2];
  const float* di = (const float*)d_in[3];
  float* out = (float*)d_out;
  const int BC = in_sizes[0] / (256 * 256);  // 512 slices
  hipLaunchKernelGGL(attn_fused15, dim3(BC), dim3(1024), 0, stream, Q, K, V,
                     di, out);
}